// Round 7
// baseline (1078.770 us; speedup 1.0000x reference)
//
#include <hip/hip_runtime.h>
#include <hip/hip_bf16.h>
#include <cstdint>
#include <cstddef>

typedef __bf16 bf16_t;
typedef __bf16 bf16x4 __attribute__((ext_vector_type(4)));
typedef __bf16 bf16x8 __attribute__((ext_vector_type(8)));
typedef float  f32x4  __attribute__((ext_vector_type(4)));

#define L_DIM 2048
#define N_DIM 8
#define E_DIM 2048
#define H_DIM 8192
#define T_DIM (L_DIM * N_DIM)   // 16384 tokens

// ---------------------------------------------------------------------------
// fp32 -> bf16 conversion
// ---------------------------------------------------------------------------
__global__ __launch_bounds__(256) void cvt_f32_bf16(const float* __restrict__ in,
                                                    bf16_t* __restrict__ out,
                                                    int n4) {
    int stride = gridDim.x * blockDim.x;
    for (int i = blockIdx.x * blockDim.x + threadIdx.x; i < n4; i += stride) {
        float4 v = *(const float4*)(in + (size_t)i * 4);
        bf16x4 o;
        o[0] = (bf16_t)v.x; o[1] = (bf16_t)v.y;
        o[2] = (bf16_t)v.z; o[3] = (bf16_t)v.w;
        *(bf16x4*)(out + (size_t)i * 4) = o;
    }
}

// ---------------------------------------------------------------------------
// Fast GELU (tanh approximation), branch-free, HW exp2/rcp.
// ---------------------------------------------------------------------------
__device__ __forceinline__ float fast_gelu(float x) {
    float x2 = x * x;
    float w  = x * __builtin_fmaf(0.1029456f, x2, 2.3022618f);
    w = fminf(w, 60.0f);
    float s = __builtin_amdgcn_exp2f(w);          // v_exp_f32
    float r = __builtin_amdgcn_rcpf(s + 1.0f);    // v_rcp_f32
    return x * s * r;
}

// ---------------------------------------------------------------------------
// Persistent 256x256 8-phase GEMM (R4/R6 schedule), with HOISTED ADDRESSES:
//  - LDS read bases precomputed in 4 VGPRs (swizzle folded in); buffer parity
//    toggled by XOR 0x10000 once per K-iter; every fragment read is
//    base + compile-time immediate -> ds_read offset:, zero per-read VALU.
//  - STAGE source pointers precomputed per output tile (cur + next tile,
//    4 each: {A,B} x {half}); per stage: select(cur,next) + kt*128.
// Sync schedule (barriers, lgkmcnt, vmcnt positions), staging layout, LDS
// swizzle, parity discipline byte-identical to the verified R4/R6 kernel.
// Dummy tail stages target the clamped last tile (valid memory, dead buffer).
// ---------------------------------------------------------------------------
template <bool GELU_OUT, int LG_NT, int LG_TN, int LG_NTILE, int KDIM, int NDIM>
__global__ __launch_bounds__(512, 2) void gemm256(const bf16_t* __restrict__ Am,
                                                  const bf16_t* __restrict__ Bm,
                                                  const float* __restrict__ bias,
                                                  void* __restrict__ Cout) {
    extern __shared__ char lds[];
    constexpr int NT    = 1 << LG_NT;      // K-tiles per output tile (KDIM/64)
    constexpr int ntile = 1 << LG_NTILE;   // output tiles per block

    const int tid  = threadIdx.x;
    const int lane = tid & 63;
    const int wid  = tid >> 6;
    const int wr   = wid >> 2;   // 0..1
    const int wc   = wid & 3;    // 0..3

    // XCD-aware bijective swizzle over the fixed 256-block grid (q = 32)
    const int wgb = (blockIdx.x & 7) * 32 + (blockIdx.x >> 3);
    const int g0  = wgb << LG_NTILE;

    // staging lane geometry (unchanged): row_in_half = wid*8 + (lane>>3),
    // pre-swizzled logical col slot = (lane&7) ^ (row&7)
    const int srow  = wid * 8 + (lane >> 3);
    const int scol8 = ((lane & 7) ^ (lane >> 3)) * 8;

    // ---- hoisted LDS read bases (parity bit 0x10000 toggles per K-iter) ----
    const int l15 = lane & 15;
    const int sl0 = ((lane >> 4)    ) ^ (lane & 7);   // 16B slot, kk=0
    const int sl1 = (4 + (lane >> 4)) ^ (lane & 7);   // 16B slot, kk=1
    unsigned rdA_[2], rdB_[2];
    rdA_[0] = (unsigned)((wr * 32 + l15) * 128 + sl0 * 16);
    rdA_[1] = (unsigned)((wr * 32 + l15) * 128 + sl1 * 16);
    rdB_[0] = (unsigned)(32768 + (wc * 64 + l15) * 128 + sl0 * 16);
    rdB_[1] = (unsigned)(32768 + (wc * 64 + l15) * 128 + sl1 * 16);

    // A frag m (row base (m>>1)*64 + (m&1)*16) -> byte imm (m>>1)*8192+(m&1)*2048
    auto ldsA = [&](int m, int kk) -> bf16x8 {
        return *(const bf16x8*)(lds + rdA_[kk] + ((m >> 1) * 8192 + (m & 1) * 2048));
    };
    auto ldsB = [&](int n, int kk) -> bf16x8 {
        return *(const bf16x8*)(lds + rdB_[kk] + n * 2048);
    };

    // ---- hoisted global staging pointers: [isB][half], current & next tile ----
    const bf16_t* curp[2][2];
    const bf16_t* nxtp[2][2];
    auto setPtrs = [&](int g, const bf16_t* (&p)[2][2]) {
        const size_t rb = (size_t)(g >> LG_TN) << 8;
        const size_t cb = (size_t)(g & ((1 << LG_TN) - 1)) << 8;
        p[0][0] = Am + (rb + (size_t)srow)         * (size_t)KDIM + scol8;
        p[0][1] = Am + (rb + (size_t)(128 + srow)) * (size_t)KDIM + scol8;
        p[1][0] = Bm + (cb + (size_t)srow)         * (size_t)KDIM + scol8;
        p[1][1] = Bm + (cb + (size_t)(128 + srow)) * (size_t)KDIM + scol8;
    };

#define GLL(src, dofs)                                                          \
    __builtin_amdgcn_global_load_lds(                                           \
        (const __attribute__((address_space(1))) void*)(src),                   \
        (__attribute__((address_space(3))) void*)(lds + (dofs)), 16, 0, 0)

    // stage half-tile: 2 loads; LDS dest = par<<16 | isB<<15 | half<<14 | wid<<10
#define STAGE_P(isB, half, par, ptr, kt) do {                                   \
        const bf16_t* s0_ = (ptr) + ((kt) << 6);                                \
        const unsigned d_ = ((unsigned)(par) << 16) | ((unsigned)(isB) << 15)   \
                          | ((unsigned)(half) << 14) | ((unsigned)wid << 10);   \
        GLL(s0_, d_);                                                           \
        GLL(s0_ + (size_t)64 * KDIM, d_ + 8192);                                \
    } while (0)

    f32x4 acc[8][4] = {};

    // Prologue: slot 0 complete (B0,B1,A0,A1) + slot 1 partial (B0,B1,A0)
    setPtrs(g0, curp);
    STAGE_P(1, 0, 0, curp[1][0], 0); STAGE_P(1, 1, 0, curp[1][1], 0);
    STAGE_P(0, 0, 0, curp[0][0], 0); STAGE_P(0, 1, 0, curp[0][1], 0);
    STAGE_P(1, 0, 1, curp[1][0], 1); STAGE_P(1, 1, 1, curp[1][1], 1);
    STAGE_P(0, 0, 1, curp[0][0], 1);
    asm volatile("s_waitcnt vmcnt(6)" ::: "memory");   // slot 0 landed
    __builtin_amdgcn_s_barrier();

    for (int ti = 0; ti < ntile; ++ti) {
        // next-tile pointers (clamped at the end -> dummies re-read last tile)
        setPtrs((ti < ntile - 1) ? (g0 + ti + 1) : (g0 + ntile - 1), nxtp);

        for (int t = 0; t < NT; ++t) {
            bf16x8 bf[4][2];
            bf16x8 af[2][2];

            // ---- phase 0: all B (8) + A m=0,1 (4); stage A1(slot u+1) ----
#pragma unroll
            for (int n = 0; n < 4; ++n)
#pragma unroll
                for (int kk = 0; kk < 2; ++kk)
                    bf[n][kk] = ldsB(n, kk);
#pragma unroll
            for (int mm = 0; mm < 2; ++mm)
#pragma unroll
                for (int kk = 0; kk < 2; ++kk)
                    af[mm][kk] = ldsA(mm, kk);
            STAGE_P(0, 1, (t & 1) ^ 1,
                    (t < NT - 1) ? curp[0][1] : nxtp[0][1], (t + 1) & (NT - 1));
            asm volatile("s_waitcnt lgkmcnt(8)" ::: "memory");
            __builtin_amdgcn_s_barrier();
            asm volatile("s_waitcnt lgkmcnt(0)" ::: "memory");
            __builtin_amdgcn_s_setprio(1);
#pragma unroll
            for (int mm = 0; mm < 2; ++mm)
#pragma unroll
                for (int n = 0; n < 4; ++n)
#pragma unroll
                    for (int kk = 0; kk < 2; ++kk)
                        acc[mm][n] = __builtin_amdgcn_mfma_f32_16x16x32_bf16(
                            af[mm][kk], bf[n][kk], acc[mm][n], 0, 0, 0);
            __builtin_amdgcn_s_setprio(0);
            __builtin_amdgcn_s_barrier();

            // ---- phases 1..3: A m=2p,2p+1; stage B0/B1/A0 of slot u+2 ----
#pragma unroll
            for (int ph = 1; ph < 4; ++ph) {
#pragma unroll
                for (int mm = 0; mm < 2; ++mm)
#pragma unroll
                    for (int kk = 0; kk < 2; ++kk)
                        af[mm][kk] = ldsA(ph * 2 + mm, kk);
                {
                    const int kt2  = (t + 2) & (NT - 1);
                    const bool nx  = (t >= NT - 2);
                    if (ph == 1)      STAGE_P(1, 0, t & 1, nx ? nxtp[1][0] : curp[1][0], kt2);
                    else if (ph == 2) STAGE_P(1, 1, t & 1, nx ? nxtp[1][1] : curp[1][1], kt2);
                    else {            STAGE_P(0, 0, t & 1, nx ? nxtp[0][0] : curp[0][0], kt2);
                                      asm volatile("s_waitcnt vmcnt(6)" ::: "memory"); }
                }
                __builtin_amdgcn_s_barrier();
                asm volatile("s_waitcnt lgkmcnt(0)" ::: "memory");
                __builtin_amdgcn_s_setprio(1);
#pragma unroll
                for (int mm = 0; mm < 2; ++mm)
#pragma unroll
                    for (int n = 0; n < 4; ++n)
#pragma unroll
                        for (int kk = 0; kk < 2; ++kk)
                            acc[ph * 2 + mm][n] = __builtin_amdgcn_mfma_f32_16x16x32_bf16(
                                af[mm][kk], bf[n][kk], acc[ph * 2 + mm][n], 0, 0, 0);
                __builtin_amdgcn_s_setprio(0);
                __builtin_amdgcn_s_barrier();
            }

            // toggle LDS read buffer parity
            rdA_[0] ^= 0x10000u; rdA_[1] ^= 0x10000u;
            rdB_[0] ^= 0x10000u; rdB_[1] ^= 0x10000u;
        }

        // ---- per-tile epilogue (reg-only, no LDS; no extra barrier needed) ----
        const int g = g0 + ti;
        const size_t rowBase = (size_t)(g >> LG_TN) << 8;
        const size_t colBase = (size_t)(g & ((1 << LG_TN) - 1)) << 8;
        const int orow = (lane >> 4) * 4;
        const int ocol = lane & 15;
#pragma unroll
        for (int m = 0; m < 8; ++m) {
            const size_t rb = rowBase + (size_t)((m >> 1) * 64 + wr * 32 + (m & 1) * 16 + orow);
#pragma unroll
            for (int n = 0; n < 4; ++n) {
                const size_t col = colBase + (size_t)(wc * 64 + n * 16 + ocol);
                const float bv = bias[col];
#pragma unroll
                for (int j = 0; j < 4; ++j) {
                    float v = acc[m][n][j] + bv;
                    if constexpr (GELU_OUT) {
                        ((bf16_t*)Cout)[(rb + j) * (size_t)NDIM + col] = (bf16_t)fast_gelu(v);
                    } else {
                        ((float*)Cout)[(rb + j) * (size_t)NDIM + col] = v;
                    }
                }
                acc[m][n] = (f32x4){0.f, 0.f, 0.f, 0.f};
            }
        }

        // advance: current tile <- next tile
        curp[0][0] = nxtp[0][0]; curp[0][1] = nxtp[0][1];
        curp[1][0] = nxtp[1][0]; curp[1][1] = nxtp[1][1];
    }
    asm volatile("s_waitcnt vmcnt(0)" ::: "memory");   // drain tail dummy loads
#undef STAGE_P
#undef GLL
}

// ---------------------------------------------------------------------------
extern "C" void kernel_launch(void* const* d_in, const int* in_sizes, int n_in,
                              void* d_out, int out_size, void* d_ws, size_t ws_size,
                              hipStream_t stream) {
    const float* x  = (const float*)d_in[0];  // [16384, 2048]
    const float* p1 = (const float*)d_in[1];  // [8192, 2048]
    const float* b1 = (const float*)d_in[2];  // [8192]
    const float* p2 = (const float*)d_in[3];  // [2048, 8192]
    const float* b2 = (const float*)d_in[4];  // [2048]
    // d_in[5] = gate_w, unused (routing is identity on the output)
    float* out = (float*)d_out;

    char* ws = (char*)d_ws;
    bf16_t* xb  = (bf16_t*)(ws);                          // 64 MB
    bf16_t* p1b = (bf16_t*)(ws + ((size_t)64 << 20));     // 32 MB
    bf16_t* p2b = (bf16_t*)(ws + ((size_t)96 << 20));     // 32 MB
    bf16_t* h   = (bf16_t*)(ws + ((size_t)128 << 20));    // 256 MB

    // GEMM1: [T,E] x [H,E]^T -> h.  2048 tiles = 256 blocks x 8 tiles.
    auto g1 = gemm256<true, 5, 5, 3, E_DIM, H_DIM>;
    // GEMM2: [T,H] x [E,H]^T -> out. 512 tiles = 256 blocks x 2 tiles.
    auto g2 = gemm256<false, 7, 3, 1, H_DIM, E_DIM>;

    (void)hipFuncSetAttribute((const void*)g1,
                              hipFuncAttributeMaxDynamicSharedMemorySize, 131072);
    (void)hipFuncSetAttribute((const void*)g2,
                              hipFuncAttributeMaxDynamicSharedMemorySize, 131072);

    cvt_f32_bf16<<<2048, 256, 0, stream>>>(x,  xb,  (T_DIM * E_DIM) / 4);
    cvt_f32_bf16<<<1024, 256, 0, stream>>>(p1, p1b, (H_DIM * E_DIM) / 4);
    cvt_f32_bf16<<<1024, 256, 0, stream>>>(p2, p2b, (E_DIM * H_DIM) / 4);

    g1<<<256, 512, 131072, stream>>>(xb, p1b, b1, (void*)h);
    g2<<<256, 512, 131072, stream>>>(h, p2b, b2, (void*)out);
}